// Round 2
// baseline (452.490 us; speedup 1.0000x reference)
//
#include <hip/hip_runtime.h>

// ---------------------------------------------------------------------------
// LoRA forward: out = x @ W^T + 2 * (x @ A^T) @ B^T
//   x:[4,4096,2048] f32, W:[2048,2048] f32, A:[16,2048] f32, B:[2048,16] f32
// R2 strategy:
//   1) W_eff = bf16(W + 2 * B @ A)                 (tiny kernel, RNE)
//   2) out = x @ W_eff^T in ONE GEMM kernel:
//        - X staged fp32->bf16 in-kernel (register cvt, ds_write_b128)
//        - As padded to stride 40 elems -> conflict-free b128 fragment reads
//        - W_eff staged via global_load_lds width=16 (m97 fast path)
//        - XCD-aware block swizzle for L2-resident staging traffic
// ---------------------------------------------------------------------------

typedef __bf16 bf16x8 __attribute__((ext_vector_type(8)));
typedef float  f32x4  __attribute__((ext_vector_type(4)));
typedef unsigned short u16x8 __attribute__((ext_vector_type(8)));

#define AS1C(p) ((const __attribute__((address_space(1))) void*)(p))
#define AS3(p)  ((__attribute__((address_space(3))) void*)(p))

__device__ __forceinline__ unsigned short f2bf_rne(float f) {
  unsigned int u = __float_as_uint(f);
  u += 0x7FFFu + ((u >> 16) & 1u);
  return (unsigned short)(u >> 16);
}
// round-half-up: 1 add + pack (cheaper in the GEMM hot loop; |err| <= 0.5 ulp)
__device__ __forceinline__ unsigned short f2bf_rhu(float f) {
  return (unsigned short)((__float_as_uint(f) + 0x8000u) >> 16);
}

constexpr int M_ = 16384;   // 4 * 4096
constexpr int N_ = 2048;    // D_out
constexpr int K_ = 2048;    // D_in
constexpr int R_ = 16;
constexpr float SCALING = 2.0f;  // 32/16

constexpr int BM = 128, BN = 128, BK = 32;
constexpr int APAD = 40;  // As row stride in elems: 80 B = 20 banks -> conflict-free b128

// ---- kernel 1: W_eff = bf16(W + 2 * B @ A), [N,K] row-major -----------------
__global__ __launch_bounds__(256) void weff_kernel(const float* __restrict__ W,
                                                   const float* __restrict__ A,
                                                   const float* __restrict__ Bl,
                                                   unsigned short* __restrict__ out) {
  int idx = blockIdx.x * blockDim.x + threadIdx.x;  // over N_*K_
  int o = idx >> 11;        // / 2048
  int d = idx & 2047;       // % 2048
  float acc = W[idx];
#pragma unroll
  for (int r = 0; r < R_; ++r)
    acc = fmaf(SCALING * Bl[o * R_ + r], A[r * K_ + d], acc);
  out[idx] = f2bf_rne(acc);
}

// ---- kernel 2: C[M,N] = x[M,K](f32) @ W_eff[N,K]^T  -------------------------
// 256 threads = 4 waves; block tile 128x128; wave tile 64x64 (4x4 MFMA 16x16x32)
__global__ __launch_bounds__(256) void gemm_kernel(const float* __restrict__ X,
                                                   const unsigned short* __restrict__ W,
                                                   float* __restrict__ C) {
  __shared__ __align__(16) unsigned short As[BM * APAD];  // 10 KB, stride-40 rows
  __shared__ __align__(16) unsigned short Bs[BN * BK];    // 8 KB, row-major [128][32]

  const int tid  = threadIdx.x;
  const int wave = tid >> 6;
  const int lane = tid & 63;

  // XCD-aware swizzle: grid is (16,128); id%8 ~ XCD. Give each XCD a
  // contiguous stripe of 16 row-blocks x all 16 col-blocks so per-K-phase
  // staging working set (~400 KB) lives in that XCD's 4 MB L2.
  const int id   = blockIdx.x + gridDim.x * blockIdx.y;
  const int xcd  = id & 7;
  const int slot = id >> 3;              // 0..255
  const int bm   = (xcd * 16 + (slot >> 4)) * BM;
  const int bn   = (slot & 15) * BN;

  const int wm = (wave & 1) * 64;   // wave's row offset in block tile
  const int wn = (wave >> 1) * 64;  // wave's col offset

  f32x4 acc[4][4] = {};

  // --- X staging (register cvt path): thread t covers rows rr and rr+64,
  //     k-segment sg2*8..+8 (8 floats = 32 B global, 16 B bf16 in LDS)
  const int rr  = tid >> 2;   // 0..63
  const int sg2 = tid & 3;    // 0..3
  const float* xg0 = X + (size_t)(bm + rr) * K_ + sg2 * 8;
  const float* xg1 = X + (size_t)(bm + 64 + rr) * K_ + sg2 * 8;
  unsigned short* wA0 = &As[rr * APAD + sg2 * 8];
  unsigned short* wA1 = &As[(rr + 64) * APAD + sg2 * 8];

  // --- W staging via global_load_lds: wave fills 32 rows, lane L -> row L/4, seg L%4
  const int rq = lane >> 2;  // 0..15
  const int sg = lane & 3;   // 0..3
  const unsigned short* wg0 = W + (size_t)(bn + wave * 32 + rq) * K_ + sg * 8;
  const unsigned short* wg1 = W + (size_t)(bn + wave * 32 + 16 + rq) * K_ + sg * 8;
  unsigned short* lb0 = &Bs[(wave * 32) * BK];        // wave-uniform LDS bases
  unsigned short* lb1 = &Bs[(wave * 32 + 16) * BK];

  // MFMA fragment addressing: A[m = lane&15][k = (lane>>4)*8 + j]
  const int fm = lane & 15;
  const int fk = (lane >> 4) * 8;

  for (int k0 = 0; k0 < K_; k0 += BK) {
    // issue global loads first so DMA + vmem overlap
    float4 a0 = *(const float4*)(xg0 + k0);
    float4 a1 = *(const float4*)(xg0 + k0 + 4);
    float4 b0 = *(const float4*)(xg1 + k0);
    float4 b1 = *(const float4*)(xg1 + k0 + 4);
    __builtin_amdgcn_global_load_lds(AS1C(wg0 + k0), AS3(lb0), 16, 0, 0);
    __builtin_amdgcn_global_load_lds(AS1C(wg1 + k0), AS3(lb1), 16, 0, 0);

    u16x8 pa, pb;
    pa[0] = f2bf_rhu(a0.x); pa[1] = f2bf_rhu(a0.y); pa[2] = f2bf_rhu(a0.z); pa[3] = f2bf_rhu(a0.w);
    pa[4] = f2bf_rhu(a1.x); pa[5] = f2bf_rhu(a1.y); pa[6] = f2bf_rhu(a1.z); pa[7] = f2bf_rhu(a1.w);
    pb[0] = f2bf_rhu(b0.x); pb[1] = f2bf_rhu(b0.y); pb[2] = f2bf_rhu(b0.z); pb[3] = f2bf_rhu(b0.w);
    pb[4] = f2bf_rhu(b1.x); pb[5] = f2bf_rhu(b1.y); pb[6] = f2bf_rhu(b1.z); pb[7] = f2bf_rhu(b1.w);
    *(u16x8*)wA0 = pa;
    *(u16x8*)wA1 = pb;

    __syncthreads();

    bf16x8 af[4], bfr[4];
#pragma unroll
    for (int i = 0; i < 4; ++i)
      af[i] = *(const bf16x8*)&As[(wm + i * 16 + fm) * APAD + fk];
#pragma unroll
    for (int j = 0; j < 4; ++j)
      bfr[j] = *(const bf16x8*)&Bs[(wn + j * 16 + fm) * BK + fk];

#pragma unroll
    for (int i = 0; i < 4; ++i)
#pragma unroll
      for (int j = 0; j < 4; ++j)
        acc[i][j] = __builtin_amdgcn_mfma_f32_16x16x32_bf16(af[i], bfr[j], acc[i][j], 0, 0, 0);

    __syncthreads();
  }

  // epilogue: C/D layout col = lane&15, row = (lane>>4)*4 + r
  const int r0   = (lane >> 4) * 4;
  const int col0 = lane & 15;
#pragma unroll
  for (int i = 0; i < 4; ++i) {
#pragma unroll
    for (int j = 0; j < 4; ++j) {
      size_t base = (size_t)(bm + wm + i * 16 + r0) * N_ + (size_t)(bn + wn + j * 16 + col0);
#pragma unroll
      for (int r = 0; r < 4; ++r)
        C[base + (size_t)r * N_] = acc[i][j][r];
    }
  }
}

extern "C" void kernel_launch(void* const* d_in, const int* in_sizes, int n_in,
                              void* d_out, int out_size, void* d_ws, size_t ws_size,
                              hipStream_t stream) {
  const float* x  = (const float*)d_in[0];  // [4,4096,2048]
  const float* W  = (const float*)d_in[1];  // [2048,2048]
  const float* A  = (const float*)d_in[2];  // [16,2048]
  const float* Bl = (const float*)d_in[3];  // [2048,16]
  float* out = (float*)d_out;               // [4,4096,2048] f32

  unsigned short* Weff = (unsigned short*)d_ws;  // [2048,2048] bf16 = 8 MB

  // 1) fold LoRA into weight
  weff_kernel<<<(N_ * K_) / 256, 256, 0, stream>>>(W, A, Bl, Weff);

  // 2) fused cvt+GEMM
  dim3 grid(N_ / BN, M_ / BM);  // 16 x 128 = 2048 blocks
  gemm_kernel<<<grid, 256, 0, stream>>>(x, Weff, out);
}

// Round 3
// 379.768 us; speedup vs baseline: 1.1915x; 1.1915x over previous
//
#include <hip/hip_runtime.h>

// ---------------------------------------------------------------------------
// LoRA forward: out = x @ W^T + 2 * (x @ A^T) @ B^T
//   x:[4,4096,2048] f32, W:[2048,2048] f32, A:[16,2048] f32, B:[2048,16] f32
// R3 strategy:
//   1) Xb   = bf16(x)                      (separate memory-bound convert)
//   2) W_eff= bf16(W + 2 * B @ A)          (tiny kernel)
//   3) out  = Xb @ W_eff^T  bf16 MFMA GEMM, BK=64, XOR-swizzled LDS segments
//      -> conflict-free ds_read_b128 while keeping global_load_lds width=16.
//      Nontemporal C stores to avoid evicting X/W from L2/L3.
// ---------------------------------------------------------------------------

typedef __bf16 bf16x8 __attribute__((ext_vector_type(8)));
typedef float  f32x4  __attribute__((ext_vector_type(4)));
typedef unsigned short u16x8 __attribute__((ext_vector_type(8)));

#define AS1C(p) ((const __attribute__((address_space(1))) void*)(p))
#define AS3(p)  ((__attribute__((address_space(3))) void*)(p))

__device__ __forceinline__ unsigned short f2bf_rne(float f) {
  unsigned int u = __float_as_uint(f);
  u += 0x7FFFu + ((u >> 16) & 1u);
  return (unsigned short)(u >> 16);
}

constexpr int M_ = 16384;   // 4 * 4096
constexpr int N_ = 2048;    // D_out
constexpr int K_ = 2048;    // D_in
constexpr int R_ = 16;
constexpr float SCALING = 2.0f;  // 32/16

constexpr int BM = 128, BN = 128, BK = 64;

// ---- kernel 1: x f32 -> bf16, 8 elems/thread --------------------------------
__global__ __launch_bounds__(256) void cvt_kernel(const float* __restrict__ in,
                                                  unsigned short* __restrict__ out) {
  size_t i = (size_t)blockIdx.x * blockDim.x + threadIdx.x;
  const float4* p = (const float4*)in;
  float4 a = p[2 * i];
  float4 b = p[2 * i + 1];
  u16x8 o;
  o[0] = f2bf_rne(a.x); o[1] = f2bf_rne(a.y); o[2] = f2bf_rne(a.z); o[3] = f2bf_rne(a.w);
  o[4] = f2bf_rne(b.x); o[5] = f2bf_rne(b.y); o[6] = f2bf_rne(b.z); o[7] = f2bf_rne(b.w);
  ((u16x8*)out)[i] = o;
}

// ---- kernel 2: W_eff = bf16(W + 2 * B @ A), [N,K] row-major -----------------
__global__ __launch_bounds__(256) void weff_kernel(const float* __restrict__ W,
                                                   const float* __restrict__ A,
                                                   const float* __restrict__ Bl,
                                                   unsigned short* __restrict__ out) {
  int idx = blockIdx.x * blockDim.x + threadIdx.x;  // over N_*K_
  int o = idx >> 11;        // / 2048
  int d = idx & 2047;       // % 2048
  float acc = W[idx];
#pragma unroll
  for (int r = 0; r < R_; ++r)
    acc = fmaf(SCALING * Bl[o * R_ + r], A[r * K_ + d], acc);
  out[idx] = f2bf_rne(acc);
}

// ---- kernel 3: C[M,N] = Xb[M,K] @ W_eff[N,K]^T  (bf16 in, f32 out) ----------
// 256 threads = 4 waves; block tile 128x128; BK=64 (2 MFMA k-steps per iter).
// LDS layout: row stride 64 elems (128 B); 16-B segment s_phys = (g + row) & 7
// where g is the logical k-segment. Staging via global_load_lds keeps the
// lane-contiguous LDS fill; the permutation is applied to the *global* column
// each lane fetches (same 128-B row -> still coalesced).
__global__ __launch_bounds__(256) void gemm_kernel(const unsigned short* __restrict__ X,
                                                   const unsigned short* __restrict__ W,
                                                   float* __restrict__ C) {
  __shared__ __align__(16) unsigned short As[BM * BK];  // 16 KB
  __shared__ __align__(16) unsigned short Bs[BN * BK];  // 16 KB

  const int tid  = threadIdx.x;
  const int wave = tid >> 6;
  const int lane = tid & 63;

  // XCD-aware swizzle: each XCD gets a 16-row-block stripe x all 16 col-blocks.
  const int id   = blockIdx.x + gridDim.x * blockIdx.y;
  const int xcd  = id & 7;
  const int slot = id >> 3;              // 0..255
  const int bm   = (xcd * 16 + (slot >> 4)) * BM;
  const int bn   = (slot & 15) * BN;

  const int wm = (wave & 1) * 64;   // wave's row offset in block tile
  const int wn = (wave >> 1) * 64;  // wave's col offset

  f32x4 acc[4][4] = {};

  // --- staging: wave covers 32 rows of each tile in 4 calls of 8 rows.
  // lane L -> row offset r8 = L>>3, physical seg L&7, global seg g = (L&7 - r8)&7
  const int r8 = lane >> 3;                    // 0..7
  const int gseg = ((lane & 7) - r8) & 7;      // global 16B-segment to fetch

  const unsigned short* xst = X + (size_t)(bm + wave * 32 + r8) * K_ + gseg * 8;
  const unsigned short* wst = W + (size_t)(bn + wave * 32 + r8) * K_ + gseg * 8;
  unsigned short* lA = &As[(wave * 32) * BK];  // wave-uniform LDS bases
  unsigned short* lB = &Bs[(wave * 32) * BK];

  // fragment addressing: A[m = lane&15][k = t*32 + quad*8 + j], quad = lane>>4
  const int fm   = lane & 15;
  const int quad = lane >> 4;

  for (int k0 = 0; k0 < K_; k0 += BK) {
#pragma unroll
    for (int c = 0; c < 4; ++c)
      __builtin_amdgcn_global_load_lds(AS1C(xst + (size_t)(c * 8) * K_ + k0),
                                       AS3(lA + c * 8 * BK), 16, 0, 0);
#pragma unroll
    for (int c = 0; c < 4; ++c)
      __builtin_amdgcn_global_load_lds(AS1C(wst + (size_t)(c * 8) * K_ + k0),
                                       AS3(lB + c * 8 * BK), 16, 0, 0);
    __syncthreads();

#pragma unroll
    for (int t = 0; t < 2; ++t) {
      const int sp = ((4 * t + quad + fm) & 7) * 8;  // swizzled elem offset in row
      bf16x8 af[4], bfr[4];
#pragma unroll
      for (int i = 0; i < 4; ++i)
        af[i] = *(const bf16x8*)&As[(wm + i * 16 + fm) * BK + sp];
#pragma unroll
      for (int j = 0; j < 4; ++j)
        bfr[j] = *(const bf16x8*)&Bs[(wn + j * 16 + fm) * BK + sp];

#pragma unroll
      for (int i = 0; i < 4; ++i)
#pragma unroll
        for (int j = 0; j < 4; ++j)
          acc[i][j] = __builtin_amdgcn_mfma_f32_16x16x32_bf16(af[i], bfr[j], acc[i][j], 0, 0, 0);
    }

    __syncthreads();
  }

  // epilogue: C/D layout col = lane&15, row = (lane>>4)*4 + r. Nontemporal
  // stores: C is never re-read; keep it out of L2/L3 so X/W stay resident.
  const int r0   = quad * 4;
  const int col0 = fm;
#pragma unroll
  for (int i = 0; i < 4; ++i) {
#pragma unroll
    for (int j = 0; j < 4; ++j) {
      size_t base = (size_t)(bm + wm + i * 16 + r0) * N_ + (size_t)(bn + wn + j * 16 + col0);
#pragma unroll
      for (int r = 0; r < 4; ++r)
        __builtin_nontemporal_store(acc[i][j][r], &C[base + (size_t)r * N_]);
    }
  }
}

extern "C" void kernel_launch(void* const* d_in, const int* in_sizes, int n_in,
                              void* d_out, int out_size, void* d_ws, size_t ws_size,
                              hipStream_t stream) {
  const float* x  = (const float*)d_in[0];  // [4,4096,2048]
  const float* W  = (const float*)d_in[1];  // [2048,2048]
  const float* A  = (const float*)d_in[2];  // [16,2048]
  const float* Bl = (const float*)d_in[3];  // [2048,16]
  float* out = (float*)d_out;               // [4,4096,2048] f32

  // workspace: Xb (M*K bf16 = 64 MB) | W_eff (N*K bf16 = 8 MB)
  unsigned short* Xb   = (unsigned short*)d_ws;
  unsigned short* Weff = Xb + (size_t)M_ * K_;

  cvt_kernel<<<(int)((size_t)M_ * K_ / 8 / 256), 256, 0, stream>>>(x, Xb);
  weff_kernel<<<(N_ * K_) / 256, 256, 0, stream>>>(W, A, Bl, Weff);

  dim3 grid(N_ / BN, M_ / BM);  // 16 x 128 = 2048 blocks
  gemm_kernel<<<grid, 256, 0, stream>>>(Xb, Weff, out);
}